// Round 7
// baseline (351.291 us; speedup 1.0000x reference)
//
#include <hip/hip_runtime.h>

// out[b,o,l] = sum_i x[b,i,k'(l)] * P[i,o,f'(l)],  k'=idx[l]&4095, f'=idx[l]>>12
// Phase 1: xT[b,k,i] = bf16(x[b,i,k])  (coalesced transpose+cast into d_ws)
// Phase 1b: pre-pack P into per-lane MFMA fragment layout (expanded K=256)
// Phase 2: bf16 MFMA with SWAPPED operands: D[m=l][n=o] = X_rows * P.
//   Lane then holds 4 consecutive l per acc -> direct dwordx4 stores, no C-LDS.
//   Bx double-buffered, ONE lgkmcnt+barrier per iter, counted vmcnt elsewhere.

typedef __attribute__((ext_vector_type(8))) short short8;
typedef __attribute__((ext_vector_type(4))) float floatx4;

#define NB    64
#define CIN   64
#define COUT  64
#define KDIM  4096
#define LDIM  16384
#define ITERS 4                                 // l-tiles (of 64) per block
#define BXS2  72                                // B-tile row stride in bf16 (144 B)
#define XT_BYTES ((size_t)NB * KDIM * CIN * 2)  // 33,554,432

__device__ __forceinline__ unsigned short f2bf(float f) {
  union { float f; unsigned u; } v; v.f = f;
  unsigned r = v.u + 0x7FFFu + ((v.u >> 16) & 1u);  // RNE
  return (unsigned short)(r >> 16);
}

__global__ __launch_bounds__(256) void transpose_bf16(const float* __restrict__ x,
                                                      unsigned short* __restrict__ xt) {
  __shared__ float tile[64 * 65];  // [i][k], +1 pad
  const int t = threadIdx.x;
  const int b = blockIdx.y;
  const int k0 = blockIdx.x * 64;
  const float4* x4 = (const float4*)x;
#pragma unroll
  for (int p = 0; p < 4; ++p) {
    int i  = p * 16 + (t >> 4);
    int kq = t & 15;
    float4 v = x4[(size_t)(b * CIN + i) * (KDIM / 4) + (k0 >> 2) + kq];
    tile[i * 65 + kq * 4 + 0] = v.x;
    tile[i * 65 + kq * 4 + 1] = v.y;
    tile[i * 65 + kq * 4 + 2] = v.z;
    tile[i * 65 + kq * 4 + 3] = v.w;
  }
  __syncthreads();
  unsigned int* xt32 = (unsigned int*)xt;
  const int ip = (t & 31) * 2;  // pair of i's packed into one u32 store
#pragma unroll
  for (int p = 0; p < 8; ++p) {
    int k = p * 8 + (t >> 5);
    unsigned lo = f2bf(tile[ip * 65 + k]);
    unsigned hi = f2bf(tile[(ip + 1) * 65 + k]);
    xt32[((size_t)b * KDIM + k0 + k) * (CIN / 2) + (ip >> 1)] = lo | (hi << 16);
  }
}

// Pre-pack P fragments: pb[((mt*8+kt)*64 + lane)*8 + j] = bf16(P[i][o][g])
// with o = mt*16 + (lane&15), s = kt*32 + (lane>>4)*8 + j, i = s&63, g = s>>6.
// Used as the mfma B-operand: B[k=quad*8+j][n=lane&15] = P[s][o].
__global__ __launch_bounds__(256) void prepack_afrag(const float* __restrict__ p,
                                                     unsigned short* __restrict__ pb) {
  const int t = blockIdx.x * 256 + threadIdx.x;  // 0..2047 = (mt*8+kt)*64 + lane
  const int lane = t & 63;
  const int mk = t >> 6;
  const int mt = mk >> 3, kt = mk & 7;
  const int o = mt * 16 + (lane & 15);
  const int quad = lane >> 4;
#pragma unroll
  for (int j = 0; j < 8; ++j) {
    int s = kt * 32 + quad * 8 + j;
    int i = s & 63, g = s >> 6;
    pb[t * 8 + j] = f2bf(p[(i * COUT + o) * 4 + g]);
  }
}

__global__ __launch_bounds__(256, 4) void gemm_v6(const unsigned short* __restrict__ xt,
                                                  const unsigned short* __restrict__ pb,
                                                  const int* __restrict__ idx,
                                                  float* __restrict__ out) {
  __shared__ __align__(16) unsigned short Bx[2][64 * BXS2];  // 2 x 9.2 KB
  __shared__ int fpv[2][64];

  const int t = threadIdx.x;
  // Bijective XCD swizzle (nwg=4096, 8 XCDs): same-b blocks share one XCD's L2.
  const int wg  = blockIdx.x + gridDim.x * blockIdx.y;  // 0..4095
  const int wgp = (wg & 7) * 512 + (wg >> 3);
  const int b   = wgp >> 6;
  const int xx  = wgp & 63;

  const int w = t >> 6;          // wave id = o-tile
  const int lane = t & 63;
  const int lane15 = lane & 15;
  const int quad = lane >> 4;

  // P fragments for THIS wave's o-tile (B-operand role): 32 VGPRs.
  short8 af[8];
  {
    const short8* pbv = (const short8*)pb;
#pragma unroll
    for (int kt = 0; kt < 8; ++kt)
      af[kt] = pbv[(w * 8 + kt) * 64 + lane];
  }

  const unsigned short* xb = xt + (size_t)b * KDIM * CIN;
  const int u  = t & 7;   // 16B chunk within the 128B row (contiguous per row)
  const int r1 = t >> 3;  // row pair: r1 and r1+32
  const int lb0 = xx * (ITERS * 64);

  // Prologue: rows(0) + idx(1) in flight.
  int iv1 = idx[lb0 + r1];
  int iv2 = idx[lb0 + 32 + r1];
  uint4 d0 = ((const uint4*)(xb + (size_t)(iv1 & (KDIM - 1)) * CIN))[u];
  uint4 d1 = ((const uint4*)(xb + (size_t)(iv2 & (KDIM - 1)) * CIN))[u];
  int fp1 = iv1 >> 12, fp2 = iv2 >> 12;
  int ivn1 = idx[lb0 + 64 + r1];
  int ivn2 = idx[lb0 + 96 + r1];

  const short8 z8 = {0, 0, 0, 0, 0, 0, 0, 0};

  for (int it = 0; it < ITERS; ++it) {
    const int p = it & 1;
    // Stage tile(it): counted vmcnt retires only the gathers; stores fly on.
    *(uint4*)&Bx[p][r1 * BXS2 + u * 8]        = d0;
    *(uint4*)&Bx[p][(r1 + 32) * BXS2 + u * 8] = d1;
    if (u == 0) { fpv[p][r1] = fp1; fpv[p][r1 + 32] = fp2; }
    asm volatile("s_waitcnt lgkmcnt(0)" ::: "memory");  // drains prev reads + these writes
    __builtin_amdgcn_s_barrier();
    asm volatile("" ::: "memory");

    // Prefetch rows(it+1) (addr from already-loaded ivn*) + idx(it+2).
    if (it + 1 < ITERS) {
      fp1 = ivn1 >> 12;
      fp2 = ivn2 >> 12;
      d0 = ((const uint4*)(xb + (size_t)(ivn1 & (KDIM - 1)) * CIN))[u];
      d1 = ((const uint4*)(xb + (size_t)(ivn2 & (KDIM - 1)) * CIN))[u];
      if (it + 2 < ITERS) {
        ivn1 = idx[lb0 + (it + 2) * 64 + r1];
        ivn2 = idx[lb0 + (it + 2) * 64 + 32 + r1];
      }
    }

    // ---- MFMA (swapped): D[m=l][n=o] += X[l][s] * P[s][o] ----
    floatx4 acc[4];
#pragma unroll
    for (int np = 0; np < 2; ++np) {
      const int lrA = (np * 2) * 16 + lane15;
      const int lrB = (np * 2 + 1) * 16 + lane15;
      const short8 evA = *(const short8*)&Bx[p][lrA * BXS2 + quad * 8];
      const short8 ovA = *(const short8*)&Bx[p][lrA * BXS2 + 32 + quad * 8];
      const short8 evB = *(const short8*)&Bx[p][lrB * BXS2 + quad * 8];
      const short8 ovB = *(const short8*)&Bx[p][lrB * BXS2 + 32 + quad * 8];
      const int fA = fpv[p][lrA];
      const int fB = fpv[p][lrB];
      floatx4 a0 = floatx4{0.f, 0.f, 0.f, 0.f};
      floatx4 a1 = floatx4{0.f, 0.f, 0.f, 0.f};
#pragma unroll
      for (int kt = 0; kt < 8; ++kt) {
        const short8 hA = (kt & 1) ? ovA : evA;           // compile-time pick
        const short8 hB = (kt & 1) ? ovB : evB;
        const short8 bA = (fA == (kt >> 1)) ? hA : z8;    // per-lane cndmask
        const short8 bB = (fB == (kt >> 1)) ? hB : z8;
        a0 = __builtin_amdgcn_mfma_f32_16x16x32_bf16(bA, af[kt], a0, 0, 0, 0);
        a1 = __builtin_amdgcn_mfma_f32_16x16x32_bf16(bB, af[kt], a1, 0, 0, 0);
      }
      acc[np * 2]     = a0;
      acc[np * 2 + 1] = a1;
    }

    // D layout (swapped): col(n) = lane&15 = o-offset; row(m) = quad*4+r = l-offset.
    // Lane's 4 acc values per nt are CONSECUTIVE l -> one dwordx4 store each.
    const int l_base = lb0 + it * 64;
    float* orow = out + ((size_t)(b * COUT + w * 16 + lane15)) * LDIM;
#pragma unroll
    for (int nt = 0; nt < 4; ++nt) {
      __builtin_nontemporal_store(acc[nt],
          (floatx4*)&orow[l_base + nt * 16 + quad * 4]);
    }
    // dbuf: next iter stages Bx[p^1]; Bx[p] reuse at it+2 is fenced by the
    // lgkmcnt(0)+barrier at iter it+1's top (all waves' reads retired there).
  }
}

extern "C" void kernel_launch(void* const* d_in, const int* in_sizes, int n_in,
                              void* d_out, int out_size, void* d_ws, size_t ws_size,
                              hipStream_t stream) {
  const float* x      = (const float*)d_in[0];   // [64,64,1,4096] fp32
  const float* params = (const float*)d_in[1];   // [64,64,4] fp32
  const int*   idx    = (const int*)d_in[2];     // [16384] int32
  float* out = (float*)d_out;                    // [64,64,1,16384] fp32
  unsigned short* xt = (unsigned short*)d_ws;                       // 33.5 MB
  unsigned short* pb = (unsigned short*)((char*)d_ws + XT_BYTES);   // 32 KB

  transpose_bf16<<<dim3(KDIM / 64, NB), 256, 0, stream>>>(x, xt);
  prepack_afrag<<<dim3(8), 256, 0, stream>>>(params, pb);
  gemm_v6<<<dim3(LDIM / (64 * ITERS), NB), 256, 0, stream>>>(xt, pb, idx, out);
}

// Round 8
// 322.813 us; speedup vs baseline: 1.0882x; 1.0882x over previous
//
#include <hip/hip_runtime.h>

// out[b,o,l] = sum_i x[b,i,k'(l)] * P[i,o,f'(l)],  k'=idx[l]&4095, f'=idx[l]>>12
// Phase 1: xT[b,k,i] = bf16(x[b,i,k])  (coalesced transpose+cast into d_ws)
// Phase 1b: pre-pack P into per-lane MFMA fragment layout (expanded K=256)
// Phase 2: bf16 MFMA, swapped operands (D[m=l][n=o]) -> b128 C->LDS writes;
//   WAVE-PRIVATE C readback (no 2nd barrier) -> 256-B-contiguous dwordx4
//   global stores (full 128-B lines). Bx double-buffered, 1 barrier/iter.

typedef __attribute__((ext_vector_type(8))) short short8;
typedef __attribute__((ext_vector_type(4))) float floatx4;

#define NB    64
#define CIN   64
#define COUT  64
#define KDIM  4096
#define LDIM  16384
#define ITERS 4                                 // l-tiles (of 64) per block
#define BXS2  72                                // B-tile row stride in bf16 (144 B)
#define CSTR  68                                // C-tile row stride in f32 (272 B)
#define XT_BYTES ((size_t)NB * KDIM * CIN * 2)  // 33,554,432

__device__ __forceinline__ unsigned short f2bf(float f) {
  union { float f; unsigned u; } v; v.f = f;
  unsigned r = v.u + 0x7FFFu + ((v.u >> 16) & 1u);  // RNE
  return (unsigned short)(r >> 16);
}

__global__ __launch_bounds__(256) void transpose_bf16(const float* __restrict__ x,
                                                      unsigned short* __restrict__ xt) {
  __shared__ float tile[64 * 65];  // [i][k], +1 pad
  const int t = threadIdx.x;
  const int b = blockIdx.y;
  const int k0 = blockIdx.x * 64;
  const float4* x4 = (const float4*)x;
#pragma unroll
  for (int p = 0; p < 4; ++p) {
    int i  = p * 16 + (t >> 4);
    int kq = t & 15;
    float4 v = x4[(size_t)(b * CIN + i) * (KDIM / 4) + (k0 >> 2) + kq];
    tile[i * 65 + kq * 4 + 0] = v.x;
    tile[i * 65 + kq * 4 + 1] = v.y;
    tile[i * 65 + kq * 4 + 2] = v.z;
    tile[i * 65 + kq * 4 + 3] = v.w;
  }
  __syncthreads();
  unsigned int* xt32 = (unsigned int*)xt;
  const int ip = (t & 31) * 2;  // pair of i's packed into one u32 store
#pragma unroll
  for (int p = 0; p < 8; ++p) {
    int k = p * 8 + (t >> 5);
    unsigned lo = f2bf(tile[ip * 65 + k]);
    unsigned hi = f2bf(tile[(ip + 1) * 65 + k]);
    xt32[((size_t)b * KDIM + k0 + k) * (CIN / 2) + (ip >> 1)] = lo | (hi << 16);
  }
}

// Pre-pack P fragments: pb[((mt*8+kt)*64 + lane)*8 + j] = bf16(P[i][o][g])
// with o = mt*16 + (lane&15), s = kt*32 + (lane>>4)*8 + j, i = s&63, g = s>>6.
// Used as the mfma B-operand: B[k=quad*8+j][n=lane&15] = P[s][o].
__global__ __launch_bounds__(256) void prepack_afrag(const float* __restrict__ p,
                                                     unsigned short* __restrict__ pb) {
  const int t = blockIdx.x * 256 + threadIdx.x;  // 0..2047 = (mt*8+kt)*64 + lane
  const int lane = t & 63;
  const int mk = t >> 6;
  const int mt = mk >> 3, kt = mk & 7;
  const int o = mt * 16 + (lane & 15);
  const int quad = lane >> 4;
#pragma unroll
  for (int j = 0; j < 8; ++j) {
    int s = kt * 32 + quad * 8 + j;
    int i = s & 63, g = s >> 6;
    pb[t * 8 + j] = f2bf(p[(i * COUT + o) * 4 + g]);
  }
}

__global__ __launch_bounds__(256, 4) void gemm_v7(const unsigned short* __restrict__ xt,
                                                  const unsigned short* __restrict__ pb,
                                                  const int* __restrict__ idx,
                                                  float* __restrict__ out) {
  __shared__ __align__(16) unsigned short Bx[2][64 * BXS2];  // 2 x 9.2 KB
  __shared__ int fpv[2][64];
  __shared__ __align__(16) float Cl[64 * CSTR];              // 17.4 KB, wave-private rows

  const int t = threadIdx.x;
  // Bijective XCD swizzle (nwg=4096, 8 XCDs): same-b blocks share one XCD's L2.
  const int wg  = blockIdx.x + gridDim.x * blockIdx.y;  // 0..4095
  const int wgp = (wg & 7) * 512 + (wg >> 3);
  const int b   = wgp >> 6;
  const int xx  = wgp & 63;

  const int w = t >> 6;          // wave id = o-tile
  const int lane = t & 63;
  const int lane15 = lane & 15;
  const int quad = lane >> 4;

  // P fragments for THIS wave's o-tile (B-operand role): 32 VGPRs.
  short8 af[8];
  {
    const short8* pbv = (const short8*)pb;
#pragma unroll
    for (int kt = 0; kt < 8; ++kt)
      af[kt] = pbv[(w * 8 + kt) * 64 + lane];
  }

  const unsigned short* xb = xt + (size_t)b * KDIM * CIN;
  const int u  = t & 7;   // 16B chunk within the 128B row (contiguous per row)
  const int r1 = t >> 3;  // row pair: r1 and r1+32
  const int lb0 = xx * (ITERS * 64);

  // Prologue: rows(0) + idx(1) in flight.
  int iv1 = idx[lb0 + r1];
  int iv2 = idx[lb0 + 32 + r1];
  uint4 d0 = ((const uint4*)(xb + (size_t)(iv1 & (KDIM - 1)) * CIN))[u];
  uint4 d1 = ((const uint4*)(xb + (size_t)(iv2 & (KDIM - 1)) * CIN))[u];
  int fp1 = iv1 >> 12, fp2 = iv2 >> 12;
  int ivn1 = idx[lb0 + 64 + r1];
  int ivn2 = idx[lb0 + 96 + r1];

  const short8 z8 = {0, 0, 0, 0, 0, 0, 0, 0};

  for (int it = 0; it < ITERS; ++it) {
    const int p = it & 1;
    // Stage tile(it): counted vmcnt retires only the gathers; stores fly on.
    *(uint4*)&Bx[p][r1 * BXS2 + u * 8]        = d0;
    *(uint4*)&Bx[p][(r1 + 32) * BXS2 + u * 8] = d1;
    if (u == 0) { fpv[p][r1] = fp1; fpv[p][r1 + 32] = fp2; }
    asm volatile("s_waitcnt lgkmcnt(0)" ::: "memory");  // drains prev reads + these writes
    __builtin_amdgcn_s_barrier();
    asm volatile("" ::: "memory");

    // Prefetch rows(it+1) (addr from already-loaded ivn*) + idx(it+2).
    if (it + 1 < ITERS) {
      fp1 = ivn1 >> 12;
      fp2 = ivn2 >> 12;
      d0 = ((const uint4*)(xb + (size_t)(ivn1 & (KDIM - 1)) * CIN))[u];
      d1 = ((const uint4*)(xb + (size_t)(ivn2 & (KDIM - 1)) * CIN))[u];
      if (it + 2 < ITERS) {
        ivn1 = idx[lb0 + (it + 2) * 64 + r1];
        ivn2 = idx[lb0 + (it + 2) * 64 + 32 + r1];
      }
    }

    // ---- MFMA (swapped): D[m=l][n=o] += X[l][s] * P[s][o] ----
    floatx4 acc[4];
#pragma unroll
    for (int np = 0; np < 2; ++np) {
      const int lrA = (np * 2) * 16 + lane15;
      const int lrB = (np * 2 + 1) * 16 + lane15;
      const short8 evA = *(const short8*)&Bx[p][lrA * BXS2 + quad * 8];
      const short8 ovA = *(const short8*)&Bx[p][lrA * BXS2 + 32 + quad * 8];
      const short8 evB = *(const short8*)&Bx[p][lrB * BXS2 + quad * 8];
      const short8 ovB = *(const short8*)&Bx[p][lrB * BXS2 + 32 + quad * 8];
      const int fA = fpv[p][lrA];
      const int fB = fpv[p][lrB];
      floatx4 a0 = floatx4{0.f, 0.f, 0.f, 0.f};
      floatx4 a1 = floatx4{0.f, 0.f, 0.f, 0.f};
#pragma unroll
      for (int kt = 0; kt < 8; ++kt) {
        const short8 hA = (kt & 1) ? ovA : evA;           // compile-time pick
        const short8 hB = (kt & 1) ? ovB : evB;
        const short8 bA = (fA == (kt >> 1)) ? hA : z8;    // per-lane cndmask
        const short8 bB = (fB == (kt >> 1)) ? hB : z8;
        a0 = __builtin_amdgcn_mfma_f32_16x16x32_bf16(bA, af[kt], a0, 0, 0, 0);
        a1 = __builtin_amdgcn_mfma_f32_16x16x32_bf16(bB, af[kt], a1, 0, 0, 0);
      }
      acc[np * 2]     = a0;
      acc[np * 2 + 1] = a1;
    }

    // ---- C -> LDS: lane holds 4 CONSECUTIVE l per nt -> one b128 write each.
    // Row o = w*16+lane15 (wave-private). Bank-balanced at CSTR=68 (8/bank).
#pragma unroll
    for (int nt = 0; nt < 4; ++nt)
      *(floatx4*)&Cl[(w * 16 + lane15) * CSTR + nt * 16 + quad * 4] = acc[nt];

    // ---- wave-private readback (no barrier: same-wave DS ordering) ----
    // 16 lanes cover 256 contiguous B of one o-row; 4 rows per instruction.
    const int l_base = lb0 + it * 64;
    const int cc = lane15 * 4;
#pragma unroll
    for (int pp = 0; pp < 4; ++pp) {
      const int row = w * 16 + pp * 4 + quad;
      floatx4 v = *(const floatx4*)&Cl[row * CSTR + cc];
      __builtin_nontemporal_store(v,
          (floatx4*)&out[((size_t)(b * COUT + row)) * LDIM + l_base + cc]);
    }
    // dbuf: next iter stages Bx[p^1]; Bx[p] reuse at it+2 is fenced by the
    // lgkmcnt(0)+barrier at iter it+1's top. Cl is wave-private throughout.
  }
}

extern "C" void kernel_launch(void* const* d_in, const int* in_sizes, int n_in,
                              void* d_out, int out_size, void* d_ws, size_t ws_size,
                              hipStream_t stream) {
  const float* x      = (const float*)d_in[0];   // [64,64,1,4096] fp32
  const float* params = (const float*)d_in[1];   // [64,64,4] fp32
  const int*   idx    = (const int*)d_in[2];     // [16384] int32
  float* out = (float*)d_out;                    // [64,64,1,16384] fp32
  unsigned short* xt = (unsigned short*)d_ws;                       // 33.5 MB
  unsigned short* pb = (unsigned short*)((char*)d_ws + XT_BYTES);   // 32 KB

  transpose_bf16<<<dim3(KDIM / 64, NB), 256, 0, stream>>>(x, xt);
  prepack_afrag<<<dim3(8), 256, 0, stream>>>(params, pb);
  gemm_v7<<<dim3(LDIM / (64 * ITERS), NB), 256, 0, stream>>>(xt, pb, idx, out);
}